// Round 1
// baseline (389.954 us; speedup 1.0000x reference)
//
#include <hip/hip_runtime.h>

#define NCH 1024

// ---------------------------------------------------------------------------
// The whole reference net is LINEAR in its inputs. We fold everything into
// per-input weight tensors (precomputed on-device each launch, ~0.5 GFLOP),
// then the timed work is 4 big dot products (~416 MB of HBM reads).
//
// ws layout (floats):
//   P  @ 0        : 1024*9        per-channel class weights
//   A  @ 16384    : 3*200704      weight maps for x1, x2, share  (14x14/chan)
//   G3 @ +602112  : 200704        weight map for x3p (post-1x1-conv space)
//   V  @ +200704  : 250880        G3 folded through c_w   [1280 x 196]
//   U  @ +250880  : 1003520       V folded through avgpool^T [1280 x 784]
//   total ~8.3 MB
// ---------------------------------------------------------------------------

// K1: per-channel class weights P[c][hc][wc]; also init out[b] = lin_b.
__global__ void k1_weights(const float* __restrict__ w3,
                           const float* __restrict__ lin_w,
                           const float* __restrict__ lin_b,
                           float* __restrict__ P,
                           float* __restrict__ out) {
  int c = blockIdx.x * blockDim.x + threadIdx.x;
  if (blockIdx.x == 0 && threadIdx.x < 64) out[threadIdx.x] = lin_b[0];
  if (c >= NCH) return;
  int dd = c & 63, ich = c >> 6;
  // depth conv: input depth dd touched by exactly one (d, kd): 3d-4+kd == dd
  int kd = (dd + 4) % 3;
  int d  = (dd + 4 - kd) / 3;
  float weff[9];
#pragma unroll
  for (int k = 0; k < 9; ++k) weff[k] = 0.f;
  for (int o = 0; o < 32; ++o) {
    float lw = lin_w[o * 24 + d];
    const float* wp = w3 + (((o * 16 + ich) * 3 + kd) * 9);
#pragma unroll
    for (int k = 0; k < 9; ++k) weff[k] += lw * wp[k];
  }
  const float inv196 = 1.f / 196.f;
#pragma unroll
  for (int k = 0; k < 9; ++k) weff[k] *= inv196;
  // spatial mean of 3x3 conv: pixel row-class 0 (h==0) -> kh in {0,1},
  // mid -> {0,1,2}, class 2 (h==13) -> {1,2}; same for columns.
  float rh[3][3];
#pragma unroll
  for (int kw = 0; kw < 3; ++kw) {
    rh[0][kw] = weff[0 * 3 + kw] + weff[1 * 3 + kw];
    rh[1][kw] = weff[0 * 3 + kw] + weff[1 * 3 + kw] + weff[2 * 3 + kw];
    rh[2][kw] = weff[1 * 3 + kw] + weff[2 * 3 + kw];
  }
#pragma unroll
  for (int hc = 0; hc < 3; ++hc) {
    P[c * 9 + hc * 3 + 0] = rh[hc][0] + rh[hc][1];
    P[c * 9 + hc * 3 + 1] = rh[hc][0] + rh[hc][1] + rh[hc][2];
    P[c * 9 + hc * 3 + 2] = rh[hc][1] + rh[hc][2];
  }
}

// K2: scatter the 7x7 class-weight windows into 14x14 per-channel maps,
// one map per gathered tensor (quadrant position fixes the edge classes).
__global__ void k2_maps(const float* __restrict__ P,
                        const int* __restrict__ idx_h,
                        const int* __restrict__ idx_w,
                        float* __restrict__ A1,
                        float* __restrict__ A2,
                        float* __restrict__ As,
                        float* __restrict__ G3) {
  int c = blockIdx.x;
  int t = threadIdx.x;
  if (t >= 196) return;
  int h = t / 14, w = t % 14;
  float p[9];
#pragma unroll
  for (int k = 0; k < 9; ++k) p[k] = P[c * 9 + k];
  {  // g1: global (h, w) = (i, j)  -> top-left quadrant
    int i = h - idx_h[0 * NCH + c], j = w - idx_w[0 * NCH + c];
    bool in = (i >= 0 && i < 7 && j >= 0 && j < 7);
    int hc = (i == 0) ? 0 : 1, wc = (j == 0) ? 0 : 1;
    A1[c * 196 + t] = in ? p[hc * 3 + wc] : 0.f;
  }
  {  // g2: global (i+7, j)  -> bottom-left
    int i = h - idx_h[1 * NCH + c], j = w - idx_w[1 * NCH + c];
    bool in = (i >= 0 && i < 7 && j >= 0 && j < 7);
    int hc = (i == 6) ? 2 : 1, wc = (j == 0) ? 0 : 1;
    A2[c * 196 + t] = in ? p[hc * 3 + wc] : 0.f;
  }
  {  // gs: global (i+7, j+7) -> bottom-right
    int i = h - idx_h[3 * NCH + c], j = w - idx_w[3 * NCH + c];
    bool in = (i >= 0 && i < 7 && j >= 0 && j < 7);
    int hc = (i == 6) ? 2 : 1, wc = (j == 6) ? 2 : 1;
    As[c * 196 + t] = in ? p[hc * 3 + wc] : 0.f;
  }
  {  // g3: global (i, j+7) -> top-right (applies to x3p channels)
    int i = h - idx_h[2 * NCH + c], j = w - idx_w[2 * NCH + c];
    bool in = (i >= 0 && i < 7 && j >= 0 && j < 7);
    int hc = (i == 0) ? 0 : 1, wc = (j == 6) ? 2 : 1;
    G3[c * 196 + t] = in ? p[hc * 3 + wc] : 0.f;
  }
}

// K3: V[cc][p] = sum_c c_w[c*1280+cc] * G3[c*196+p]   (1280x196, K=1024 GEMM)
#define K3_CCT 64
#define K3_PT 16
#define K3_KT 64
__global__ void k3_vgemm(const float* __restrict__ c_w,
                         const float* __restrict__ G3,
                         float* __restrict__ V) {
  __shared__ float cwT[K3_KT][K3_CCT];  // 16 KB
  __shared__ float g3t[K3_KT][K3_PT];   // 4 KB
  int cc0 = blockIdx.x * K3_CCT;
  int p0 = blockIdx.y * K3_PT;
  int tid = threadIdx.x;
  int cc = tid & 63;
  int pg = tid >> 6;  // 0..3
  float acc[4] = {0.f, 0.f, 0.f, 0.f};
  for (int k0 = 0; k0 < NCH; k0 += K3_KT) {
#pragma unroll
    for (int r = 0; r < 16; ++r) {
      int idx = r * 256 + tid;
      int kk = idx >> 6, c2 = idx & 63;
      cwT[kk][c2] = c_w[(size_t)(k0 + kk) * 1280 + cc0 + c2];
    }
#pragma unroll
    for (int r = 0; r < 4; ++r) {
      int idx = r * 256 + tid;
      int kk = idx >> 4, pp = idx & 15;
      int p = p0 + pp;
      g3t[kk][pp] = (p < 196) ? G3[(size_t)(k0 + kk) * 196 + p] : 0.f;
    }
    __syncthreads();
#pragma unroll 8
    for (int kk = 0; kk < K3_KT; ++kk) {
      float a = cwT[kk][cc];
#pragma unroll
      for (int u = 0; u < 4; ++u) acc[u] += a * g3t[kk][pg * 4 + u];
    }
    __syncthreads();
  }
#pragma unroll
  for (int u = 0; u < 4; ++u) {
    int p = p0 + pg * 4 + u;
    if (p < 196) V[(size_t)(cc0 + cc) * 196 + p] = acc[u];
  }
}

// K4: U[cc][H][W] = (1/25) * sum over pool outputs (h,w) whose 5x5 window
// (stride 2, pad 2) covers input pixel (H,W) of V[cc][h][w].
__global__ void k4_unpool(const float* __restrict__ V, float* __restrict__ U) {
  int cc = blockIdx.x;
  for (int t = threadIdx.x; t < 784; t += blockDim.x) {
    int H = t / 28, W = t % 28;
    int hlo = (H - 1) / 2; if (hlo < 0) hlo = 0;
    int hhi = (H + 2) / 2; if (hhi > 13) hhi = 13;
    int wlo = (W - 1) / 2; if (wlo < 0) wlo = 0;
    int whi = (W + 2) / 2; if (whi > 13) whi = 13;
    float s = 0.f;
    for (int h = hlo; h <= hhi; ++h)
      for (int w = wlo; w <= whi; ++w)
        s += V[(size_t)cc * 196 + h * 14 + w];
    U[(size_t)cc * 784 + t] = s * 0.04f;
  }
}

__device__ __forceinline__ void block_reduce_atomic(float s, float* out, int b) {
#pragma unroll
  for (int off = 32; off > 0; off >>= 1) s += __shfl_down(s, off, 64);
  __shared__ float red[4];
  int lane = threadIdx.x & 63, wid = threadIdx.x >> 6;
  if (lane == 0) red[wid] = s;
  __syncthreads();
  if (threadIdx.x == 0) atomicAdd(&out[b], red[0] + red[1] + red[2] + red[3]);
}

// K5: fused dot products for the three [B,1024,14,14] tensors.
__global__ void k5_dot3(const float* __restrict__ x1,
                        const float* __restrict__ x2,
                        const float* __restrict__ xs,
                        const float* __restrict__ Amaps,
                        float* __restrict__ out) {
  const int nf4 = 200704 / 4;
  int z = blockIdx.z;
  const float* x = (z == 0) ? x1 : (z == 1) ? x2 : xs;
  int b = blockIdx.y;
  const float4* xb = reinterpret_cast<const float4*>(x) + (size_t)b * nf4;
  const float4* Ab = reinterpret_cast<const float4*>(Amaps) + (size_t)z * nf4;
  float s = 0.f;
  for (int i = blockIdx.x * blockDim.x + threadIdx.x; i < nf4;
       i += gridDim.x * blockDim.x) {
    float4 xv = xb[i], av = Ab[i];
    s += xv.x * av.x + xv.y * av.y + xv.z * av.z + xv.w * av.w;
  }
  block_reduce_atomic(s, out, b);
}

// K6: dot product for x3 [B,1280,28,28] against U.
__global__ void k6_dotx3(const float* __restrict__ x3,
                         const float* __restrict__ U,
                         float* __restrict__ out) {
  const int nf4 = 1003520 / 4;
  int b = blockIdx.y;
  const float4* xb = reinterpret_cast<const float4*>(x3) + (size_t)b * nf4;
  const float4* Ub = reinterpret_cast<const float4*>(U);
  float s = 0.f;
  for (int i = blockIdx.x * blockDim.x + threadIdx.x; i < nf4;
       i += gridDim.x * blockDim.x) {
    float4 xv = xb[i], uv = Ub[i];
    s += xv.x * uv.x + xv.y * uv.y + xv.z * uv.z + xv.w * uv.w;
  }
  block_reduce_atomic(s, out, b);
}

extern "C" void kernel_launch(void* const* d_in, const int* in_sizes, int n_in,
                              void* d_out, int out_size, void* d_ws, size_t ws_size,
                              hipStream_t stream) {
  const float* x1 = (const float*)d_in[0];
  const float* x2 = (const float*)d_in[1];
  const float* x3 = (const float*)d_in[2];
  const float* sf = (const float*)d_in[3];
  const float* c_w = (const float*)d_in[4];
  const float* w3 = (const float*)d_in[5];
  const float* lin_w = (const float*)d_in[6];
  const float* lin_b = (const float*)d_in[7];
  const int* idx_h = (const int*)d_in[8];
  const int* idx_w = (const int*)d_in[9];
  float* out = (float*)d_out;
  float* ws = (float*)d_ws;

  float* P = ws;              // 1024*9
  float* A = ws + 16384;      // 3 * 200704 (A1, A2, As contiguous)
  float* G3 = A + 3 * 200704; // 200704
  float* V = G3 + 200704;     // 1280*196
  float* U = V + 250880;      // 1280*784

  k1_weights<<<dim3(4), dim3(256), 0, stream>>>(w3, lin_w, lin_b, P, out);
  k2_maps<<<dim3(1024), dim3(256), 0, stream>>>(P, idx_h, idx_w, A, A + 200704,
                                                A + 2 * 200704, G3);
  k3_vgemm<<<dim3(20, 13), dim3(256), 0, stream>>>(c_w, G3, V);
  k4_unpool<<<dim3(1280), dim3(256), 0, stream>>>(V, U);
  k5_dot3<<<dim3(49, 64, 3), dim3(256), 0, stream>>>(x1, x2, sf, A, out);
  k6_dotx3<<<dim3(245, 64), dim3(256), 0, stream>>>(x3, U, out);
}

// Round 2
// 296.980 us; speedup vs baseline: 1.3131x; 1.3131x over previous
//
#include <hip/hip_runtime.h>

#define NCH 1024

// ---------------------------------------------------------------------------
// The whole reference net is LINEAR in its inputs. Fold everything into
// per-input weight tensors (precomputed on-device, ~0.5 GFLOP), then the
// timed work is 4 big dot products (~416 MB of HBM reads), reduced without
// atomics via per-block partials + one tiny final-sum kernel.
//
// ws layout (floats):
//   A    @ 0        : 3*200704   weight maps for x1, x2, share
//   G3   @ 602112   : 200704     weight map for x3p (post-1x1-conv space)
//   V    @ 802816   : 250880     G3 folded through c_w      [1280 x 196]
//   U    @ 1053696  : 1003520    V folded through avgpool^T [1280 x 28 x 28]
//   part @ 2057216  : 4096       per-block dot partials [4][64][16]
// ---------------------------------------------------------------------------

// K12: fused per-channel class weights + scatter into 14x14 weight maps.
__global__ void k12_maps(const float* __restrict__ w3,
                         const float* __restrict__ lin_w,
                         const int* __restrict__ idx_h,
                         const int* __restrict__ idx_w,
                         float* __restrict__ A1,
                         float* __restrict__ A2,
                         float* __restrict__ As,
                         float* __restrict__ G3) {
  int c = blockIdx.x;
  int t = threadIdx.x;
  if (t >= 196) return;
  // --- per-channel class weights (every thread redundantly, in registers) ---
  int dd = c & 63, ich = c >> 6;
  // depth conv (stride 3, pad 4): input depth dd touched by exactly one
  // (d, kd) with 3d-4+kd == dd
  int kd = (dd + 4) % 3;
  int d  = (dd + 4 - kd) / 3;
  float weff[9];
#pragma unroll
  for (int k = 0; k < 9; ++k) weff[k] = 0.f;
  for (int o = 0; o < 32; ++o) {
    float lw = lin_w[o * 24 + d];
    const float* wp = w3 + (((o * 16 + ich) * 3 + kd) * 9);
#pragma unroll
    for (int k = 0; k < 9; ++k) weff[k] += lw * wp[k];
  }
  const float inv196 = 1.f / 196.f;
#pragma unroll
  for (int k = 0; k < 9; ++k) weff[k] *= inv196;
  // spatial mean of 3x3 conv: row-class 0 (h==0) -> kh in {0,1},
  // mid -> {0,1,2}, class 2 (h==13) -> {1,2}; same for columns.
  float rh[3][3];
#pragma unroll
  for (int kw = 0; kw < 3; ++kw) {
    rh[0][kw] = weff[0 * 3 + kw] + weff[1 * 3 + kw];
    rh[1][kw] = weff[0 * 3 + kw] + weff[1 * 3 + kw] + weff[2 * 3 + kw];
    rh[2][kw] = weff[1 * 3 + kw] + weff[2 * 3 + kw];
  }
  float p[9];
#pragma unroll
  for (int hc = 0; hc < 3; ++hc) {
    p[hc * 3 + 0] = rh[hc][0] + rh[hc][1];
    p[hc * 3 + 1] = rh[hc][0] + rh[hc][1] + rh[hc][2];
    p[hc * 3 + 2] = rh[hc][1] + rh[hc][2];
  }
  // --- scatter 7x7 windows into the 14x14 maps (quadrant fixes edge class) ---
  int h = t / 14, w = t % 14;
  {  // g1 -> top-left quadrant of the 14x14 concat
    int i = h - idx_h[0 * NCH + c], j = w - idx_w[0 * NCH + c];
    bool in = (i >= 0 && i < 7 && j >= 0 && j < 7);
    int hc = (i == 0) ? 0 : 1, wc = (j == 0) ? 0 : 1;
    A1[c * 196 + t] = in ? p[hc * 3 + wc] : 0.f;
  }
  {  // g2 -> bottom-left
    int i = h - idx_h[1 * NCH + c], j = w - idx_w[1 * NCH + c];
    bool in = (i >= 0 && i < 7 && j >= 0 && j < 7);
    int hc = (i == 6) ? 2 : 1, wc = (j == 0) ? 0 : 1;
    A2[c * 196 + t] = in ? p[hc * 3 + wc] : 0.f;
  }
  {  // gs -> bottom-right
    int i = h - idx_h[3 * NCH + c], j = w - idx_w[3 * NCH + c];
    bool in = (i >= 0 && i < 7 && j >= 0 && j < 7);
    int hc = (i == 6) ? 2 : 1, wc = (j == 6) ? 2 : 1;
    As[c * 196 + t] = in ? p[hc * 3 + wc] : 0.f;
  }
  {  // g3 -> top-right (applies to x3p channels, pre-1x1-conv fold)
    int i = h - idx_h[2 * NCH + c], j = w - idx_w[2 * NCH + c];
    bool in = (i >= 0 && i < 7 && j >= 0 && j < 7);
    int hc = (i == 0) ? 0 : 1, wc = (j == 6) ? 2 : 1;
    G3[c * 196 + t] = in ? p[hc * 3 + wc] : 0.f;
  }
}

// K3: V[cc][p] = sum_c c_w[c*1280+cc] * G3[c*196+p]   (1280x196, K=1024)
#define K3_CCT 64
#define K3_PT 16
#define K3_KT 64
__global__ void k3_vgemm(const float* __restrict__ c_w,
                         const float* __restrict__ G3,
                         float* __restrict__ V) {
  __shared__ float cwT[K3_KT][K3_CCT];  // 16 KB
  __shared__ float g3t[K3_KT][K3_PT];   // 4 KB
  int cc0 = blockIdx.x * K3_CCT;
  int p0 = blockIdx.y * K3_PT;
  int tid = threadIdx.x;
  int cc = tid & 63;
  int pg = tid >> 6;  // 0..3
  float acc[4] = {0.f, 0.f, 0.f, 0.f};
  for (int k0 = 0; k0 < NCH; k0 += K3_KT) {
#pragma unroll
    for (int r = 0; r < 16; ++r) {
      int idx = r * 256 + tid;
      int kk = idx >> 6, c2 = idx & 63;
      cwT[kk][c2] = c_w[(size_t)(k0 + kk) * 1280 + cc0 + c2];
    }
#pragma unroll
    for (int r = 0; r < 4; ++r) {
      int idx = r * 256 + tid;
      int kk = idx >> 4, pp = idx & 15;
      int p = p0 + pp;
      g3t[kk][pp] = (p < 196) ? G3[(size_t)(k0 + kk) * 196 + p] : 0.f;
    }
    __syncthreads();
#pragma unroll 8
    for (int kk = 0; kk < K3_KT; ++kk) {
      float a = cwT[kk][cc];
#pragma unroll
      for (int u = 0; u < 4; ++u) acc[u] += a * g3t[kk][pg * 4 + u];
    }
    __syncthreads();
  }
#pragma unroll
  for (int u = 0; u < 4; ++u) {
    int p = p0 + pg * 4 + u;
    if (p < 196) V[(size_t)(cc0 + cc) * 196 + p] = acc[u];
  }
}

// K4: U[cc][H][W] = (1/25) * sum over pool outputs (h,w) whose 5x5 window
// (stride 2, pad 2) covers input pixel (H,W) of V[cc][h][w].
__global__ void k4_unpool(const float* __restrict__ V, float* __restrict__ U) {
  int cc = blockIdx.x;
  for (int t = threadIdx.x; t < 784; t += blockDim.x) {
    int H = t / 28, W = t % 28;
    int hlo = (H - 1) / 2; if (hlo < 0) hlo = 0;
    int hhi = (H + 2) / 2; if (hhi > 13) hhi = 13;
    int wlo = (W - 1) / 2; if (wlo < 0) wlo = 0;
    int whi = (W + 2) / 2; if (whi > 13) whi = 13;
    float s = 0.f;
    for (int h = hlo; h <= hhi; ++h)
      for (int w = wlo; w <= whi; ++w)
        s += V[(size_t)cc * 196 + h * 14 + w];
    U[(size_t)cc * 784 + t] = s * 0.04f;
  }
}

// KDOT: all four dot products. blockIdx.z picks the tensor; partials go to
// ws (no atomics). part[((z*64+b)<<4) + blockIdx.x], fully overwritten.
__global__ void kdot(const float* __restrict__ x1,
                     const float* __restrict__ x2,
                     const float* __restrict__ xs,
                     const float* __restrict__ x3,
                     const float* __restrict__ A,
                     const float* __restrict__ U,
                     float* __restrict__ part) {
  int z = blockIdx.z, b = blockIdx.y;
  const float* x;
  const float* W;
  int nf4;
  if (z == 3) {
    x = x3 + (size_t)b * 1003520;
    W = U;
    nf4 = 1003520 / 4;
  } else {
    const float* xt = (z == 0) ? x1 : (z == 1) ? x2 : xs;
    x = xt + (size_t)b * 200704;
    W = A + (size_t)z * 200704;
    nf4 = 200704 / 4;
  }
  const float4* xv = reinterpret_cast<const float4*>(x);
  const float4* wv = reinterpret_cast<const float4*>(W);
  float s = 0.f;
  for (int i = blockIdx.x * blockDim.x + threadIdx.x; i < nf4;
       i += gridDim.x * blockDim.x) {
    float4 a = xv[i], w = wv[i];
    s += a.x * w.x + a.y * w.y + a.z * w.z + a.w * w.w;
  }
#pragma unroll
  for (int off = 32; off > 0; off >>= 1) s += __shfl_down(s, off, 64);
  __shared__ float red[4];
  int lane = threadIdx.x & 63, wid = threadIdx.x >> 6;
  if (lane == 0) red[wid] = s;
  __syncthreads();
  if (threadIdx.x == 0)
    part[((z * 64 + b) << 4) + blockIdx.x] = red[0] + red[1] + red[2] + red[3];
}

// K7: out[b] = lin_b + sum of 64 partials. One block, 64 threads.
__global__ void k7_final(const float* __restrict__ part,
                         const float* __restrict__ lin_b,
                         float* __restrict__ out) {
  int b = threadIdx.x;
  if (b >= 64) return;
  float s = lin_b[0];
  for (int z = 0; z < 4; ++z)
#pragma unroll
    for (int cx = 0; cx < 16; ++cx) s += part[((z * 64 + b) << 4) + cx];
  out[b] = s;
}

extern "C" void kernel_launch(void* const* d_in, const int* in_sizes, int n_in,
                              void* d_out, int out_size, void* d_ws, size_t ws_size,
                              hipStream_t stream) {
  const float* x1 = (const float*)d_in[0];
  const float* x2 = (const float*)d_in[1];
  const float* x3 = (const float*)d_in[2];
  const float* sf = (const float*)d_in[3];
  const float* c_w = (const float*)d_in[4];
  const float* w3 = (const float*)d_in[5];
  const float* lin_w = (const float*)d_in[6];
  const float* lin_b = (const float*)d_in[7];
  const int* idx_h = (const int*)d_in[8];
  const int* idx_w = (const int*)d_in[9];
  float* out = (float*)d_out;
  float* ws = (float*)d_ws;

  float* A = ws;                   // 3 * 200704
  float* G3 = A + 3 * 200704;      // 200704
  float* V = G3 + 200704;          // 1280*196
  float* U = V + 250880;           // 1280*784
  float* part = U + 1003520;       // 4*64*16

  k12_maps<<<dim3(1024), dim3(256), 0, stream>>>(w3, lin_w, idx_h, idx_w,
                                                 A, A + 200704, A + 2 * 200704, G3);
  k3_vgemm<<<dim3(20, 13), dim3(256), 0, stream>>>(c_w, G3, V);
  k4_unpool<<<dim3(1280), dim3(256), 0, stream>>>(V, U);
  kdot<<<dim3(16, 64, 4), dim3(256), 0, stream>>>(x1, x2, sf, x3, A, U, part);
  k7_final<<<dim3(1), dim3(64), 0, stream>>>(part, lin_b, out);
}

// Round 3
// 178.426 us; speedup vs baseline: 2.1855x; 1.6644x over previous
//
#include <hip/hip_runtime.h>

#define NCH 1024

// ---------------------------------------------------------------------------
// The net is LINEAR in its inputs: fold all weights into per-input weight
// tensors (precomputed on-device, ~0.7 GFLOP), then the timed work is 4 big
// dot products (~411 MB of HBM reads) with deep memory-level parallelism.
//
// ws layout (floats):
//   P9   @ 0        : 1024*9     per-channel class weights
//   A    @ 16384    : 3*200704   weight maps for x1, x2, share
//   G3   @ 618496   : 200704     weight map for x3p (post-1x1-conv space)
//   V    @ 819200   : 250880     G3 folded through c_w      [1280 x 196]
//   U    @ 1070080  : 1003520    V folded through avgpool^T [1280 x 28 x 28]
//   part @ 2073600  : 16384      per-block dot partials [4][64][64]
// ---------------------------------------------------------------------------

// K1: per-channel class weights P9[c][hc][wc].
__global__ void k1_weights(const float* __restrict__ w3,
                           const float* __restrict__ lin_w,
                           float* __restrict__ P9) {
  int c = blockIdx.x * 64 + threadIdx.x;
  if (c >= NCH) return;
  int dd = c & 63, ich = c >> 6;
  // depth conv (stride 3, pad 4): input depth dd hit by exactly one (d, kd)
  int kd = (dd + 4) % 3;
  int d  = (dd + 4 - kd) / 3;
  float weff[9];
#pragma unroll
  for (int k = 0; k < 9; ++k) weff[k] = 0.f;
  for (int o = 0; o < 32; ++o) {
    float lw = lin_w[o * 24 + d];
    const float* wp = w3 + (((o * 16 + ich) * 3 + kd) * 9);
#pragma unroll
    for (int k = 0; k < 9; ++k) weff[k] += lw * wp[k];
  }
  const float inv196 = 1.f / 196.f;
#pragma unroll
  for (int k = 0; k < 9; ++k) weff[k] *= inv196;
  // spatial mean of 3x3 conv: edge classes. row-class 0 -> kh in {0,1},
  // mid -> {0,1,2}, class 2 -> {1,2}; same for columns.
  float rh[3][3];
#pragma unroll
  for (int kw = 0; kw < 3; ++kw) {
    rh[0][kw] = weff[0 * 3 + kw] + weff[1 * 3 + kw];
    rh[1][kw] = weff[0 * 3 + kw] + weff[1 * 3 + kw] + weff[2 * 3 + kw];
    rh[2][kw] = weff[1 * 3 + kw] + weff[2 * 3 + kw];
  }
#pragma unroll
  for (int hc = 0; hc < 3; ++hc) {
    P9[c * 9 + hc * 3 + 0] = rh[hc][0] + rh[hc][1];
    P9[c * 9 + hc * 3 + 1] = rh[hc][0] + rh[hc][1] + rh[hc][2];
    P9[c * 9 + hc * 3 + 2] = rh[hc][1] + rh[hc][2];
  }
}

// K2: scatter 7x7 class-weight windows into 14x14 per-channel weight maps.
__global__ void k2_maps(const float* __restrict__ P9,
                        const int* __restrict__ idx_h,
                        const int* __restrict__ idx_w,
                        float* __restrict__ A1,
                        float* __restrict__ A2,
                        float* __restrict__ As,
                        float* __restrict__ G3) {
  int c = blockIdx.x;
  int t = threadIdx.x;
  if (t >= 196) return;
  float p[9];
#pragma unroll
  for (int k = 0; k < 9; ++k) p[k] = P9[c * 9 + k];
  int h = t / 14, w = t % 14;
  {  // g1 -> top-left quadrant
    int i = h - idx_h[0 * NCH + c], j = w - idx_w[0 * NCH + c];
    bool in = (i >= 0 && i < 7 && j >= 0 && j < 7);
    int hc = (i == 0) ? 0 : 1, wc = (j == 0) ? 0 : 1;
    A1[c * 196 + t] = in ? p[hc * 3 + wc] : 0.f;
  }
  {  // g2 -> bottom-left
    int i = h - idx_h[1 * NCH + c], j = w - idx_w[1 * NCH + c];
    bool in = (i >= 0 && i < 7 && j >= 0 && j < 7);
    int hc = (i == 6) ? 2 : 1, wc = (j == 0) ? 0 : 1;
    A2[c * 196 + t] = in ? p[hc * 3 + wc] : 0.f;
  }
  {  // gs -> bottom-right
    int i = h - idx_h[3 * NCH + c], j = w - idx_w[3 * NCH + c];
    bool in = (i >= 0 && i < 7 && j >= 0 && j < 7);
    int hc = (i == 6) ? 2 : 1, wc = (j == 6) ? 2 : 1;
    As[c * 196 + t] = in ? p[hc * 3 + wc] : 0.f;
  }
  {  // g3 -> top-right (pre-1x1-conv fold space)
    int i = h - idx_h[2 * NCH + c], j = w - idx_w[2 * NCH + c];
    bool in = (i >= 0 && i < 7 && j >= 0 && j < 7);
    int hc = (i == 0) ? 0 : 1, wc = (j == 6) ? 2 : 1;
    G3[c * 196 + t] = in ? p[hc * 3 + wc] : 0.f;
  }
}

// K3: V[cc][p] = sum_c c_w[c*1280+cc] * G3[c*196+p]. One wave per block
// (exclusive LDS pipe), 4cc x 4p register tile per lane, b128 LDS reads.
__global__ __launch_bounds__(64) void k3_vgemm(const float* __restrict__ c_w,
                                               const float* __restrict__ G3,
                                               float* __restrict__ V) {
  __shared__ float cwT[64][64];  // 16 KB
  __shared__ float g3t[64][16];  // 4 KB
  int cc0 = blockIdx.x * 64;     // 20 tiles
  int p0 = blockIdx.y * 16;      // 13 tiles (208 >= 196)
  int lane = threadIdx.x;
  int tc = lane & 15;   // cc quad
  int tp = lane >> 4;   // p quad (0..3)
  float acc[4][4];
#pragma unroll
  for (int i = 0; i < 4; ++i)
#pragma unroll
    for (int j = 0; j < 4; ++j) acc[i][j] = 0.f;
  for (int k0 = 0; k0 < NCH; k0 += 64) {
#pragma unroll
    for (int r = 0; r < 16; ++r) {  // 1024 quads of cwT
      int idx4 = r * 64 + lane;
      int kk = idx4 >> 4, c4 = idx4 & 15;
      *(float4*)&cwT[kk][c4 * 4] =
          *(const float4*)&c_w[(size_t)(k0 + kk) * 1280 + cc0 + c4 * 4];
    }
#pragma unroll
    for (int r = 0; r < 4; ++r) {  // 256 quads of g3t
      int idx4 = r * 64 + lane;
      int kk = idx4 >> 2, pq = idx4 & 3;
      int p = p0 + pq * 4;
      float4 v = (p < 196) ? *(const float4*)&G3[(size_t)(k0 + kk) * 196 + p]
                           : float4{0.f, 0.f, 0.f, 0.f};
      *(float4*)&g3t[kk][pq * 4] = v;
    }
    __syncthreads();
#pragma unroll
    for (int kk = 0; kk < 64; ++kk) {
      float4 a = *(const float4*)&cwT[kk][tc * 4];
      float4 b = *(const float4*)&g3t[kk][tp * 4];
      acc[0][0] += a.x * b.x; acc[0][1] += a.x * b.y; acc[0][2] += a.x * b.z; acc[0][3] += a.x * b.w;
      acc[1][0] += a.y * b.x; acc[1][1] += a.y * b.y; acc[1][2] += a.y * b.z; acc[1][3] += a.y * b.w;
      acc[2][0] += a.z * b.x; acc[2][1] += a.z * b.y; acc[2][2] += a.z * b.z; acc[2][3] += a.z * b.w;
      acc[3][0] += a.w * b.x; acc[3][1] += a.w * b.y; acc[3][2] += a.w * b.z; acc[3][3] += a.w * b.w;
    }
    __syncthreads();
  }
  int p = p0 + tp * 4;
  if (p < 196) {
#pragma unroll
    for (int i = 0; i < 4; ++i) {
      int cc = cc0 + tc * 4 + i;
      *(float4*)&V[(size_t)cc * 196 + p] =
          float4{acc[i][0], acc[i][1], acc[i][2], acc[i][3]};
    }
  }
}

// K4: U[cc][H][W] = (1/25) * sum of V[cc][h][w] over pool windows covering
// input pixel (H,W)  (5x5, stride 2, pad 2, count_include_pad).
__global__ void k4_unpool(const float* __restrict__ V, float* __restrict__ U) {
  int cc = blockIdx.x;
  for (int t = threadIdx.x; t < 784; t += blockDim.x) {
    int H = t / 28, W = t % 28;
    int hlo = (H - 1) / 2; if (hlo < 0) hlo = 0;
    int hhi = (H + 2) / 2; if (hhi > 13) hhi = 13;
    int wlo = (W - 1) / 2; if (wlo < 0) wlo = 0;
    int whi = (W + 2) / 2; if (whi > 13) whi = 13;
    float s = 0.f;
    for (int h = hlo; h <= hhi; ++h)
      for (int w = wlo; w <= whi; ++w)
        s += V[(size_t)cc * 196 + h * 14 + w];
    U[(size_t)cc * 784 + t] = s * 0.04f;
  }
}

// KDOT: the four dot products, chunked into identical 4096-float4 tiles with
// 16 fully-unrolled load pairs per thread (deep MLP). Partials -> ws.
// z<3: nf4=50176 = 12*4096 + 1024 (13 chunks). z=3: 250880 = 61*4096 + 1024.
__global__ __launch_bounds__(256, 2) void kdot(const float4* __restrict__ x1,
                                               const float4* __restrict__ x2,
                                               const float4* __restrict__ xs,
                                               const float4* __restrict__ x3,
                                               const float4* __restrict__ A,
                                               const float4* __restrict__ U,
                                               float* __restrict__ part) {
  int bid = blockIdx.x;
  int z, b, cx, tail;
  const float4 *xp, *wp;
  if (bid < 2496) {
    z = bid / 832;
    int r = bid % 832;
    b = r / 13;
    cx = r % 13;
    const float4* xt = (z == 0) ? x1 : (z == 1) ? x2 : xs;
    xp = xt + (size_t)b * 50176 + cx * 4096;
    wp = A + (size_t)z * 50176 + cx * 4096;
    tail = (cx == 12);
  } else {
    int r = bid - 2496;
    z = 3;
    b = r / 62;
    cx = r % 62;
    xp = x3 + (size_t)b * 250880 + cx * 4096;
    wp = U + cx * 4096;
    tail = (cx == 61);
  }
  int t = threadIdx.x;
  float s = 0.f;
  if (!tail) {
#pragma unroll
    for (int u = 0; u < 16; ++u) {
      float4 a = xp[u * 256 + t];
      float4 w = wp[u * 256 + t];
      s += a.x * w.x + a.y * w.y + a.z * w.z + a.w * w.w;
    }
  } else {
#pragma unroll
    for (int u = 0; u < 4; ++u) {
      float4 a = xp[u * 256 + t];
      float4 w = wp[u * 256 + t];
      s += a.x * w.x + a.y * w.y + a.z * w.z + a.w * w.w;
    }
  }
#pragma unroll
  for (int off = 32; off > 0; off >>= 1) s += __shfl_down(s, off, 64);
  __shared__ float red[4];
  int lane = t & 63, wid = t >> 6;
  if (lane == 0) red[wid] = s;
  __syncthreads();
  if (t == 0)
    part[((z * 64 + b) << 6) + cx] = red[0] + red[1] + red[2] + red[3];
}

// K7: out[b] = lin_b + sum of partials. One block, 64 threads.
__global__ void k7_final(const float* __restrict__ part,
                         const float* __restrict__ lin_b,
                         float* __restrict__ out) {
  int b = threadIdx.x;
  if (b >= 64) return;
  float s = lin_b[0];
  for (int z = 0; z < 3; ++z)
#pragma unroll
    for (int cx = 0; cx < 13; ++cx) s += part[((z * 64 + b) << 6) + cx];
#pragma unroll
  for (int cx = 0; cx < 62; ++cx) s += part[((3 * 64 + b) << 6) + cx];
  out[b] = s;
}

extern "C" void kernel_launch(void* const* d_in, const int* in_sizes, int n_in,
                              void* d_out, int out_size, void* d_ws, size_t ws_size,
                              hipStream_t stream) {
  const float* x1 = (const float*)d_in[0];
  const float* x2 = (const float*)d_in[1];
  const float* x3 = (const float*)d_in[2];
  const float* sf = (const float*)d_in[3];
  const float* c_w = (const float*)d_in[4];
  const float* w3 = (const float*)d_in[5];
  const float* lin_w = (const float*)d_in[6];
  const float* lin_b = (const float*)d_in[7];
  const int* idx_h = (const int*)d_in[8];
  const int* idx_w = (const int*)d_in[9];
  float* out = (float*)d_out;
  float* ws = (float*)d_ws;

  float* P9 = ws;                  // 1024*9
  float* A = ws + 16384;           // 3 * 200704
  float* G3 = A + 3 * 200704;      // 200704
  float* V = G3 + 200704;          // 1280*196
  float* U = V + 250880;           // 1280*784
  float* part = U + 1003520;       // 4*64*64

  k1_weights<<<dim3(16), dim3(64), 0, stream>>>(w3, lin_w, P9);
  k2_maps<<<dim3(1024), dim3(256), 0, stream>>>(P9, idx_h, idx_w, A, A + 200704,
                                                A + 2 * 200704, G3);
  k3_vgemm<<<dim3(20, 13), dim3(64), 0, stream>>>(c_w, G3, V);
  k4_unpool<<<dim3(1280), dim3(256), 0, stream>>>(V, U);
  kdot<<<dim3(6464), dim3(256), 0, stream>>>(
      (const float4*)x1, (const float4*)x2, (const float4*)sf,
      (const float4*)x3, (const float4*)A, (const float4*)U, part);
  k7_final<<<dim3(1), dim3(64), 0, stream>>>(part, lin_b, out);
}

// Round 4
// 144.914 us; speedup vs baseline: 2.6909x; 1.2313x over previous
//
#include <hip/hip_runtime.h>

#define NCH 1024

// ---------------------------------------------------------------------------
// The net is LINEAR in its inputs: fold all weights into per-input weight
// tensors (precomputed on-device, ~0.7 GFLOP), then the timed work is 4 big
// dot products (~411 MB HBM). kdot amortizes the weight side over 8 batches
// per block (LDS-staged) so request traffic ~= HBM-minimal.
//
// ws layout (floats):
//   A    @ 0        : 3*200704   weight maps for x1, x2, share
//   G3   @ 602112   : 200704     weight map for x3p (post-1x1-conv space)
//   Vp   @ 802816   : 8*250880   K-split partials of V [8][1280][196]
//   U    @ 2809856  : 1003520    V folded through avgpool^T [1280 x 28 x 28]
//   part @ 3813376  : 32768      per-block dot partials [256 rows][128]
// ---------------------------------------------------------------------------

// K2: fused per-channel class weights (cooperative) + scatter into 14x14 maps.
__global__ void k2_maps(const float* __restrict__ w3,
                        const float* __restrict__ lin_w,
                        const int* __restrict__ idx_h,
                        const int* __restrict__ idx_w,
                        float* __restrict__ A1,
                        float* __restrict__ A2,
                        float* __restrict__ As,
                        float* __restrict__ G3) {
  __shared__ float lweff[9];
  int c = blockIdx.x;
  int t = threadIdx.x;
  int dd = c & 63, ich = c >> 6;
  // depth conv (stride 3, pad 4): input depth dd hit by exactly one (d, kd)
  int kd = (dd + 4) % 3;
  int d  = (dd + 4 - kd) / 3;
  if (t < 9) {
    float acc = 0.f;
    for (int o = 0; o < 32; ++o)
      acc += lin_w[o * 24 + d] * w3[(((o * 16 + ich) * 3) + kd) * 9 + t];
    lweff[t] = acc * (1.f / 196.f);
  }
  __syncthreads();
  if (t >= 196) return;
  float weff[9];
#pragma unroll
  for (int k = 0; k < 9; ++k) weff[k] = lweff[k];
  // spatial mean of 3x3 conv -> 3x3 edge-class weights
  float rh[3][3];
#pragma unroll
  for (int kw = 0; kw < 3; ++kw) {
    rh[0][kw] = weff[0 * 3 + kw] + weff[1 * 3 + kw];
    rh[1][kw] = weff[0 * 3 + kw] + weff[1 * 3 + kw] + weff[2 * 3 + kw];
    rh[2][kw] = weff[1 * 3 + kw] + weff[2 * 3 + kw];
  }
  float p[9];
#pragma unroll
  for (int hc = 0; hc < 3; ++hc) {
    p[hc * 3 + 0] = rh[hc][0] + rh[hc][1];
    p[hc * 3 + 1] = rh[hc][0] + rh[hc][1] + rh[hc][2];
    p[hc * 3 + 2] = rh[hc][1] + rh[hc][2];
  }
  int h = t / 14, w = t % 14;
  {  // g1 -> top-left quadrant
    int i = h - idx_h[0 * NCH + c], j = w - idx_w[0 * NCH + c];
    bool in = (i >= 0 && i < 7 && j >= 0 && j < 7);
    int hc = (i == 0) ? 0 : 1, wc = (j == 0) ? 0 : 1;
    A1[c * 196 + t] = in ? p[hc * 3 + wc] : 0.f;
  }
  {  // g2 -> bottom-left
    int i = h - idx_h[1 * NCH + c], j = w - idx_w[1 * NCH + c];
    bool in = (i >= 0 && i < 7 && j >= 0 && j < 7);
    int hc = (i == 6) ? 2 : 1, wc = (j == 0) ? 0 : 1;
    A2[c * 196 + t] = in ? p[hc * 3 + wc] : 0.f;
  }
  {  // gs -> bottom-right
    int i = h - idx_h[3 * NCH + c], j = w - idx_w[3 * NCH + c];
    bool in = (i >= 0 && i < 7 && j >= 0 && j < 7);
    int hc = (i == 6) ? 2 : 1, wc = (j == 6) ? 2 : 1;
    As[c * 196 + t] = in ? p[hc * 3 + wc] : 0.f;
  }
  {  // g3 -> top-right (pre-1x1-conv fold space)
    int i = h - idx_h[2 * NCH + c], j = w - idx_w[2 * NCH + c];
    bool in = (i >= 0 && i < 7 && j >= 0 && j < 7);
    int hc = (i == 0) ? 0 : 1, wc = (j == 6) ? 2 : 1;
    G3[c * 196 + t] = in ? p[hc * 3 + wc] : 0.f;
  }
}

// K3: Vp[kz][cc][p] partial of V[cc][p] = sum_c c_w[c*1280+cc]*G3[c*196+p].
// 4 waves/block, 64cc x 64p tile, 8-way K-split (128 K each).
__global__ __launch_bounds__(256) void k3_vgemm(const float* __restrict__ c_w,
                                                const float* __restrict__ G3,
                                                float* __restrict__ Vp) {
  __shared__ float cwT[64][64];  // 16 KB
  __shared__ float g3t[64][64];  // 16 KB
  int cc0 = blockIdx.x * 64;   // 20
  int p0 = blockIdx.y * 64;    // 4 (256 >= 196, guarded)
  int kz = blockIdx.z;         // 8
  int tid = threadIdx.x;
  int lane = tid & 63, wid = tid >> 6;
  int tc = lane & 15;              // cc quad
  int pq = wid * 4 + (lane >> 4);  // p quad 0..15
  float acc[4][4];
#pragma unroll
  for (int i = 0; i < 4; ++i)
#pragma unroll
    for (int j = 0; j < 4; ++j) acc[i][j] = 0.f;
  for (int k0 = kz * 128; k0 < kz * 128 + 128; k0 += 64) {
#pragma unroll
    for (int r = 0; r < 4; ++r) {  // 1024 float4 of cwT
      int idx4 = r * 256 + tid;
      int kk = idx4 >> 4, c4 = idx4 & 15;
      *(float4*)&cwT[kk][c4 * 4] =
          *(const float4*)&c_w[(size_t)(k0 + kk) * 1280 + cc0 + c4 * 4];
    }
#pragma unroll
    for (int r = 0; r < 4; ++r) {  // 1024 float4 of g3t
      int idx4 = r * 256 + tid;
      int kk = idx4 >> 4, p4 = idx4 & 15;
      int p = p0 + p4 * 4;
      float4 v = (p < 196) ? *(const float4*)&G3[(size_t)(k0 + kk) * 196 + p]
                           : float4{0.f, 0.f, 0.f, 0.f};
      *(float4*)&g3t[kk][p4 * 4] = v;
    }
    __syncthreads();
#pragma unroll
    for (int kk = 0; kk < 64; ++kk) {
      float4 a = *(const float4*)&cwT[kk][tc * 4];
      float4 b = *(const float4*)&g3t[kk][pq * 4];
      acc[0][0] += a.x * b.x; acc[0][1] += a.x * b.y; acc[0][2] += a.x * b.z; acc[0][3] += a.x * b.w;
      acc[1][0] += a.y * b.x; acc[1][1] += a.y * b.y; acc[1][2] += a.y * b.z; acc[1][3] += a.y * b.w;
      acc[2][0] += a.z * b.x; acc[2][1] += a.z * b.y; acc[2][2] += a.z * b.z; acc[2][3] += a.z * b.w;
      acc[3][0] += a.w * b.x; acc[3][1] += a.w * b.y; acc[3][2] += a.w * b.z; acc[3][3] += a.w * b.w;
    }
    __syncthreads();
  }
  int p = p0 + pq * 4;
  if (p < 196) {
#pragma unroll
    for (int i = 0; i < 4; ++i) {
      int cc = cc0 + tc * 4 + i;
      *(float4*)&Vp[(size_t)kz * 250880 + (size_t)cc * 196 + p] =
          float4{acc[i][0], acc[i][1], acc[i][2], acc[i][3]};
    }
  }
}

// K4: sum the 8 K-partials of V (LDS), then unpool:
// U[cc][H][W] = (1/25) * sum of V[cc][h][w] over 5x5/s2/p2 windows covering
// (H,W), count_include_pad.
__global__ void k4_unpool(const float* __restrict__ Vp, float* __restrict__ U) {
  __shared__ float v[196];
  int cc = blockIdx.x;
  int t = threadIdx.x;
  if (t < 196) {
    float s = 0.f;
#pragma unroll
    for (int z = 0; z < 8; ++z)
      s += Vp[(size_t)z * 250880 + (size_t)cc * 196 + t];
    v[t] = s;
  }
  __syncthreads();
  for (int q = t; q < 784; q += blockDim.x) {
    int H = q / 28, W = q % 28;
    int hlo = (H - 1) / 2; if (hlo < 0) hlo = 0;
    int hhi = (H + 2) / 2; if (hhi > 13) hhi = 13;
    int wlo = (W - 1) / 2; if (wlo < 0) wlo = 0;
    int whi = (W + 2) / 2; if (whi > 13) whi = 13;
    float s = 0.f;
    for (int h = hlo; h <= hhi; ++h)
      for (int w = wlo; w <= whi; ++w) s += v[h * 14 + w];
    U[(size_t)cc * 784 + q] = s * 0.04f;
  }
}

// KDOT: weight chunk (2048 float4 = 32 KB) staged in LDS once, dotted against
// 8 batches' x-chunks. z<3: 50176 = 24*2048+1024 (25 chunks); z=3:
// 250880 = 122*2048+1024 (123 chunks). 8 b-groups. 600+984 = 1584 blocks.
__global__ __launch_bounds__(256) void kdot(const float4* __restrict__ x1,
                                            const float4* __restrict__ x2,
                                            const float4* __restrict__ xs,
                                            const float4* __restrict__ x3,
                                            const float4* __restrict__ A,
                                            const float4* __restrict__ U,
                                            float* __restrict__ part) {
  __shared__ float4 lw4[2048];
  __shared__ float red[8][4];
  int bid = blockIdx.x;
  int z, bg, cx;
  size_t stride;
  const float4 *xbase, *wbase;
  bool tail;
  if (bid < 600) {
    z = bid / 200;
    int r = bid % 200;
    bg = r / 25;
    cx = r % 25;
    const float4* xt = (z == 0) ? x1 : (z == 1) ? x2 : xs;
    stride = 50176;
    xbase = xt + (size_t)bg * 8 * 50176 + (size_t)cx * 2048;
    wbase = A + (size_t)z * 50176 + (size_t)cx * 2048;
    tail = (cx == 24);
  } else {
    int r = bid - 600;
    z = 3;
    bg = r / 123;
    cx = r % 123;
    stride = 250880;
    xbase = x3 + (size_t)bg * 8 * 250880 + (size_t)cx * 2048;
    wbase = U + (size_t)cx * 2048;
    tail = (cx == 122);
  }
  int t = threadIdx.x;
  if (!tail) {
#pragma unroll
    for (int r = 0; r < 8; ++r) lw4[r * 256 + t] = wbase[r * 256 + t];
  } else {
#pragma unroll
    for (int r = 0; r < 4; ++r) lw4[r * 256 + t] = wbase[r * 256 + t];
  }
  __syncthreads();
  float s[8] = {0.f, 0.f, 0.f, 0.f, 0.f, 0.f, 0.f, 0.f};
  if (!tail) {
#pragma unroll
    for (int u = 0; u < 8; ++u) {
      float4 w = lw4[u * 256 + t];
#pragma unroll
      for (int b = 0; b < 8; ++b) {
        float4 a = xbase[(size_t)b * stride + u * 256 + t];
        s[b] += a.x * w.x + a.y * w.y + a.z * w.z + a.w * w.w;
      }
    }
  } else {
#pragma unroll
    for (int u = 0; u < 4; ++u) {
      float4 w = lw4[u * 256 + t];
#pragma unroll
      for (int b = 0; b < 8; ++b) {
        float4 a = xbase[(size_t)b * stride + u * 256 + t];
        s[b] += a.x * w.x + a.y * w.y + a.z * w.z + a.w * w.w;
      }
    }
  }
  int lane = t & 63, wid = t >> 6;
#pragma unroll
  for (int b = 0; b < 8; ++b) {
    float v = s[b];
#pragma unroll
    for (int off = 32; off > 0; off >>= 1) v += __shfl_down(v, off, 64);
    if (lane == 0) red[b][wid] = v;
  }
  __syncthreads();
  if (t < 8) {
    float r4 = red[t][0] + red[t][1] + red[t][2] + red[t][3];
    int row = z * 64 + bg * 8 + t;
    part[(row << 7) + cx] = r4;
  }
}

// K7: out[b] = lin_b + sum of partials. One block, 64 threads.
__global__ void k7_final(const float* __restrict__ part,
                         const float* __restrict__ lin_b,
                         float* __restrict__ out) {
  int b = threadIdx.x;
  if (b >= 64) return;
  float s = lin_b[0];
  for (int z = 0; z < 3; ++z)
#pragma unroll
    for (int cx = 0; cx < 25; ++cx) s += part[((z * 64 + b) << 7) + cx];
#pragma unroll
  for (int cx = 0; cx < 123; ++cx) s += part[((192 + b) << 7) + cx];
  out[b] = s;
}

extern "C" void kernel_launch(void* const* d_in, const int* in_sizes, int n_in,
                              void* d_out, int out_size, void* d_ws, size_t ws_size,
                              hipStream_t stream) {
  const float* x1 = (const float*)d_in[0];
  const float* x2 = (const float*)d_in[1];
  const float* x3 = (const float*)d_in[2];
  const float* sf = (const float*)d_in[3];
  const float* c_w = (const float*)d_in[4];
  const float* w3 = (const float*)d_in[5];
  const float* lin_w = (const float*)d_in[6];
  const float* lin_b = (const float*)d_in[7];
  const int* idx_h = (const int*)d_in[8];
  const int* idx_w = (const int*)d_in[9];
  float* out = (float*)d_out;
  float* ws = (float*)d_ws;

  float* A = ws;                // 3*200704
  float* G3 = A + 602112;       // 200704
  float* Vp = G3 + 200704;      // 8*250880
  float* U = Vp + 2007040;      // 1280*784
  float* part = U + 1003520;    // 256*128

  k2_maps<<<dim3(1024), dim3(256), 0, stream>>>(w3, lin_w, idx_h, idx_w,
                                                A, A + 200704, A + 2 * 200704, G3);
  k3_vgemm<<<dim3(20, 4, 8), dim3(256), 0, stream>>>(c_w, G3, Vp);
  k4_unpool<<<dim3(1280), dim3(256), 0, stream>>>(Vp, U);
  kdot<<<dim3(1584), dim3(256), 0, stream>>>(
      (const float4*)x1, (const float4*)x2, (const float4*)sf,
      (const float4*)x3, (const float4*)A, (const float4*)U, part);
  k7_final<<<dim3(1), dim3(64), 0, stream>>>(part, lin_b, out);
}

// Round 6
// 140.542 us; speedup vs baseline: 2.7746x; 1.0311x over previous
//
#include <hip/hip_runtime.h>

#define NCH 1024

typedef float f4v __attribute__((ext_vector_type(4)));

// ---------------------------------------------------------------------------
// The net is LINEAR in its inputs: fold all weights into per-input weight
// tensors (precomputed on-device, ~0.7 GFLOP), then the timed work is 4 big
// dot products (~411 MB HBM). kdot: register-only streaming, 16-batch weight
// amortization, non-temporal x loads, exact 1024-float4 chunks.
//
// ws layout (floats):
//   A    @ 0        : 3*200704   weight maps for x1, x2, share
//   G3   @ 602112   : 200704     weight map for x3p (post-1x1-conv space)
//   Vp   @ 802816   : 8*250880   K-split partials of V [8][1280][196]
//   U    @ 2809856  : 1003520    V folded through avgpool^T [1280 x 28 x 28]
//   part @ 3813376  : 65536      per-block dot partials [256 rows][256]
// ---------------------------------------------------------------------------

// K2: fused per-channel class weights (cooperative) + scatter into 14x14 maps.
__global__ void k2_maps(const float* __restrict__ w3,
                        const float* __restrict__ lin_w,
                        const int* __restrict__ idx_h,
                        const int* __restrict__ idx_w,
                        float* __restrict__ A1,
                        float* __restrict__ A2,
                        float* __restrict__ As,
                        float* __restrict__ G3) {
  __shared__ float lweff[9];
  int c = blockIdx.x;
  int t = threadIdx.x;
  int dd = c & 63, ich = c >> 6;
  // depth conv (stride 3, pad 4): input depth dd hit by exactly one (d, kd)
  int kd = (dd + 4) % 3;
  int d  = (dd + 4 - kd) / 3;
  if (t < 9) {
    float acc = 0.f;
    for (int o = 0; o < 32; ++o)
      acc += lin_w[o * 24 + d] * w3[(((o * 16 + ich) * 3) + kd) * 9 + t];
    lweff[t] = acc * (1.f / 196.f);
  }
  __syncthreads();
  if (t >= 196) return;
  float weff[9];
#pragma unroll
  for (int k = 0; k < 9; ++k) weff[k] = lweff[k];
  // spatial mean of 3x3 conv -> 3x3 edge-class weights
  float rh[3][3];
#pragma unroll
  for (int kw = 0; kw < 3; ++kw) {
    rh[0][kw] = weff[0 * 3 + kw] + weff[1 * 3 + kw];
    rh[1][kw] = weff[0 * 3 + kw] + weff[1 * 3 + kw] + weff[2 * 3 + kw];
    rh[2][kw] = weff[1 * 3 + kw] + weff[2 * 3 + kw];
  }
  float p[9];
#pragma unroll
  for (int hc = 0; hc < 3; ++hc) {
    p[hc * 3 + 0] = rh[hc][0] + rh[hc][1];
    p[hc * 3 + 1] = rh[hc][0] + rh[hc][1] + rh[hc][2];
    p[hc * 3 + 2] = rh[hc][1] + rh[hc][2];
  }
  int h = t / 14, w = t % 14;
  {  // g1 -> top-left quadrant
    int i = h - idx_h[0 * NCH + c], j = w - idx_w[0 * NCH + c];
    bool in = (i >= 0 && i < 7 && j >= 0 && j < 7);
    int hc = (i == 0) ? 0 : 1, wc = (j == 0) ? 0 : 1;
    A1[c * 196 + t] = in ? p[hc * 3 + wc] : 0.f;
  }
  {  // g2 -> bottom-left
    int i = h - idx_h[1 * NCH + c], j = w - idx_w[1 * NCH + c];
    bool in = (i >= 0 && i < 7 && j >= 0 && j < 7);
    int hc = (i == 6) ? 2 : 1, wc = (j == 0) ? 0 : 1;
    A2[c * 196 + t] = in ? p[hc * 3 + wc] : 0.f;
  }
  {  // gs -> bottom-right
    int i = h - idx_h[3 * NCH + c], j = w - idx_w[3 * NCH + c];
    bool in = (i >= 0 && i < 7 && j >= 0 && j < 7);
    int hc = (i == 6) ? 2 : 1, wc = (j == 6) ? 2 : 1;
    As[c * 196 + t] = in ? p[hc * 3 + wc] : 0.f;
  }
  {  // g3 -> top-right (pre-1x1-conv fold space)
    int i = h - idx_h[2 * NCH + c], j = w - idx_w[2 * NCH + c];
    bool in = (i >= 0 && i < 7 && j >= 0 && j < 7);
    int hc = (i == 0) ? 0 : 1, wc = (j == 6) ? 2 : 1;
    G3[c * 196 + t] = in ? p[hc * 3 + wc] : 0.f;
  }
}

// K3: Vp[kz][cc][p] partial of V[cc][p] = sum_c c_w[c*1280+cc]*G3[c*196+p].
// 4 waves/block, 64cc x 64p tile, 8-way K-split (128 K each).
__global__ __launch_bounds__(256) void k3_vgemm(const float* __restrict__ c_w,
                                                const float* __restrict__ G3,
                                                float* __restrict__ Vp) {
  __shared__ float cwT[64][64];  // 16 KB
  __shared__ float g3t[64][64];  // 16 KB
  int cc0 = blockIdx.x * 64;   // 20
  int p0 = blockIdx.y * 64;    // 4 (256 >= 196, guarded)
  int kz = blockIdx.z;         // 8
  int tid = threadIdx.x;
  int lane = tid & 63, wid = tid >> 6;
  int tc = lane & 15;              // cc quad
  int pq = wid * 4 + (lane >> 4);  // p quad 0..15
  float acc[4][4];
#pragma unroll
  for (int i = 0; i < 4; ++i)
#pragma unroll
    for (int j = 0; j < 4; ++j) acc[i][j] = 0.f;
  for (int k0 = kz * 128; k0 < kz * 128 + 128; k0 += 64) {
#pragma unroll
    for (int r = 0; r < 4; ++r) {  // 1024 float4 of cwT
      int idx4 = r * 256 + tid;
      int kk = idx4 >> 4, c4 = idx4 & 15;
      *(float4*)&cwT[kk][c4 * 4] =
          *(const float4*)&c_w[(size_t)(k0 + kk) * 1280 + cc0 + c4 * 4];
    }
#pragma unroll
    for (int r = 0; r < 4; ++r) {  // 1024 float4 of g3t
      int idx4 = r * 256 + tid;
      int kk = idx4 >> 4, p4 = idx4 & 15;
      int p = p0 + p4 * 4;
      float4 v = (p < 196) ? *(const float4*)&G3[(size_t)(k0 + kk) * 196 + p]
                           : float4{0.f, 0.f, 0.f, 0.f};
      *(float4*)&g3t[kk][p4 * 4] = v;
    }
    __syncthreads();
#pragma unroll
    for (int kk = 0; kk < 64; ++kk) {
      float4 a = *(const float4*)&cwT[kk][tc * 4];
      float4 b = *(const float4*)&g3t[kk][pq * 4];
      acc[0][0] += a.x * b.x; acc[0][1] += a.x * b.y; acc[0][2] += a.x * b.z; acc[0][3] += a.x * b.w;
      acc[1][0] += a.y * b.x; acc[1][1] += a.y * b.y; acc[1][2] += a.y * b.z; acc[1][3] += a.y * b.w;
      acc[2][0] += a.z * b.x; acc[2][1] += a.z * b.y; acc[2][2] += a.z * b.z; acc[2][3] += a.z * b.w;
      acc[3][0] += a.w * b.x; acc[3][1] += a.w * b.y; acc[3][2] += a.w * b.z; acc[3][3] += a.w * b.w;
    }
    __syncthreads();
  }
  int p = p0 + pq * 4;
  if (p < 196) {
#pragma unroll
    for (int i = 0; i < 4; ++i) {
      int cc = cc0 + tc * 4 + i;
      *(float4*)&Vp[(size_t)kz * 250880 + (size_t)cc * 196 + p] =
          float4{acc[i][0], acc[i][1], acc[i][2], acc[i][3]};
    }
  }
}

// K4: sum the 8 K-partials of V (LDS), then unpool:
// U[cc][H][W] = (1/25) * sum of V[cc][h][w] over 5x5/s2/p2 windows covering
// (H,W), count_include_pad.
__global__ void k4_unpool(const float* __restrict__ Vp, float* __restrict__ U) {
  __shared__ float v[196];
  int cc = blockIdx.x;
  int t = threadIdx.x;
  if (t < 196) {
    float s = 0.f;
#pragma unroll
    for (int z = 0; z < 8; ++z)
      s += Vp[(size_t)z * 250880 + (size_t)cc * 196 + t];
    v[t] = s;
  }
  __syncthreads();
  for (int q = t; q < 784; q += blockDim.x) {
    int H = q / 28, W = q % 28;
    int hlo = (H - 1) / 2; if (hlo < 0) hlo = 0;
    int hhi = (H + 2) / 2; if (hhi > 13) hhi = 13;
    int wlo = (W - 1) / 2; if (wlo < 0) wlo = 0;
    int whi = (W + 2) / 2; if (whi > 13) whi = 13;
    float s = 0.f;
    for (int h = hlo; h <= hhi; ++h)
      for (int w = wlo; w <= whi; ++w) s += v[h * 14 + w];
    U[(size_t)cc * 784 + q] = s * 0.04f;
  }
}

// KDOT: pure register streamer. Each block: one 1024-float4 weight chunk
// (register, read per-u) x 16 batches. z<3: 49 chunks exact; z=3: 245 exact.
// bg fastest-varying so the 4 blocks sharing a chunk dispatch together.
// Blocks: 3*196 + 980 = 1568.
__global__ __launch_bounds__(256) void kdot(const f4v* __restrict__ x1,
                                            const f4v* __restrict__ x2,
                                            const f4v* __restrict__ xs,
                                            const f4v* __restrict__ x3,
                                            const f4v* __restrict__ A,
                                            const f4v* __restrict__ U,
                                            float* __restrict__ part) {
  int bid = blockIdx.x;
  int z, bg, cx;
  size_t stride;
  const f4v *xbase, *wbase;
  if (bid < 588) {
    z = bid / 196;
    int rr = bid % 196;
    cx = rr >> 2;
    bg = rr & 3;
    const f4v* xt = (z == 0) ? x1 : (z == 1) ? x2 : xs;
    stride = 50176;
    xbase = xt + (size_t)bg * 16 * 50176 + (size_t)cx * 1024;
    wbase = A + (size_t)z * 50176 + (size_t)cx * 1024;
  } else {
    int rr = bid - 588;
    z = 3;
    cx = rr >> 2;
    bg = rr & 3;
    stride = 250880;
    xbase = x3 + (size_t)bg * 16 * 250880 + (size_t)cx * 1024;
    wbase = U + (size_t)cx * 1024;
  }
  int t = threadIdx.x;
  float s[16];
#pragma unroll
  for (int i = 0; i < 16; ++i) s[i] = 0.f;
#pragma unroll
  for (int u = 0; u < 4; ++u) {
    f4v w = wbase[u * 256 + t];
#pragma unroll
    for (int b = 0; b < 16; ++b) {
      f4v a =
          __builtin_nontemporal_load(&xbase[(size_t)b * stride + u * 256 + t]);
      s[b] += a.x * w.x + a.y * w.y + a.z * w.z + a.w * w.w;
    }
  }
  int lane = t & 63, wid = t >> 6;
  __shared__ float red[16][4];
#pragma unroll
  for (int b = 0; b < 16; ++b) {
    float v = s[b];
#pragma unroll
    for (int off = 32; off > 0; off >>= 1) v += __shfl_down(v, off, 64);
    if (lane == 0) red[b][wid] = v;
  }
  __syncthreads();
  if (t < 16) {
    float r4 = red[t][0] + red[t][1] + red[t][2] + red[t][3];
    int row = z * 64 + bg * 16 + t;
    part[(row << 8) + cx] = r4;
  }
}

// K7: out[b] = lin_b + sum of partials. One block, 64 threads.
__global__ void k7_final(const float* __restrict__ part,
                         const float* __restrict__ lin_b,
                         float* __restrict__ out) {
  int b = threadIdx.x;
  if (b >= 64) return;
  float s = lin_b[0];
  for (int z = 0; z < 3; ++z)
#pragma unroll
    for (int cx = 0; cx < 49; ++cx) s += part[((z * 64 + b) << 8) + cx];
#pragma unroll
  for (int cx = 0; cx < 245; ++cx) s += part[((192 + b) << 8) + cx];
  out[b] = s;
}

extern "C" void kernel_launch(void* const* d_in, const int* in_sizes, int n_in,
                              void* d_out, int out_size, void* d_ws, size_t ws_size,
                              hipStream_t stream) {
  const float* x1 = (const float*)d_in[0];
  const float* x2 = (const float*)d_in[1];
  const float* x3 = (const float*)d_in[2];
  const float* sf = (const float*)d_in[3];
  const float* c_w = (const float*)d_in[4];
  const float* w3 = (const float*)d_in[5];
  const float* lin_w = (const float*)d_in[6];
  const float* lin_b = (const float*)d_in[7];
  const int* idx_h = (const int*)d_in[8];
  const int* idx_w = (const int*)d_in[9];
  float* out = (float*)d_out;
  float* ws = (float*)d_ws;

  float* A = ws;                // 3*200704
  float* G3 = A + 602112;       // 200704
  float* Vp = G3 + 200704;      // 8*250880
  float* U = Vp + 2007040;      // 1280*784
  float* part = U + 1003520;    // 256*256

  k2_maps<<<dim3(1024), dim3(256), 0, stream>>>(w3, lin_w, idx_h, idx_w,
                                                A, A + 200704, A + 2 * 200704, G3);
  k3_vgemm<<<dim3(20, 4, 8), dim3(256), 0, stream>>>(c_w, G3, Vp);
  k4_unpool<<<dim3(1280), dim3(256), 0, stream>>>(Vp, U);
  kdot<<<dim3(1568), dim3(256), 0, stream>>>(
      (const f4v*)x1, (const f4v*)x2, (const f4v*)sf,
      (const f4v*)x3, (const f4v*)A, (const f4v*)U, part);
  k7_final<<<dim3(1), dim3(64), 0, stream>>>(part, lin_b, out);
}